// Round 1
// baseline (1515.191 us; speedup 1.0000x reference)
//
#include <hip/hip_runtime.h>
#include <cmath>

#define BB 4
#define TT 2048
#define CC 1024
#define HH 16
#define DD 64
#define MM (BB*TT)   // 8192

// ---------------------------------------------------------------------------
// Tiled fp32 GEMM: out[M,N] = A[M,1024] @ W[1024,N] + bias[N]
// If QKV: scatter columns into q/k/v buffers with [B,H,T,D] layout.
// Block 256 threads, 128x128 tile, BK=16, 8x8 per thread (split 2x2 of 4x4).
// ---------------------------------------------------------------------------
template<int N, bool QKV>
__global__ __launch_bounds__(256)
void gemm_kernel(const float* __restrict__ A, const float* __restrict__ W,
                 const float* __restrict__ bias,
                 float* __restrict__ out,
                 float* __restrict__ qb, float* __restrict__ kb, float* __restrict__ vb)
{
    const int K = 1024;
    const int BM = 128, BN = 128, BK = 16;
    __shared__ float As[BK][BM + 4];   // transposed A tile: As[k][m]
    __shared__ float Bs[BK][BN + 4];   // Bs[k][n]

    const int tid = threadIdx.x;
    const int tx = tid & 15;
    const int ty = tid >> 4;
    const int m0 = blockIdx.y * BM;
    const int n0 = blockIdx.x * BN;

    float acc[2][2][4][4] = {};

    for (int kk = 0; kk < K; kk += BK) {
        // ---- stage A tile (128 rows x 16 cols), transposed into As[k][m] ----
        {
            const int row = tid >> 2;            // 0..63
            const int c4  = (tid & 3) * 4;       // 0,4,8,12
            float4 a0 = *(const float4*)&A[(size_t)(m0 + row) * K + kk + c4];
            float4 a1 = *(const float4*)&A[(size_t)(m0 + row + 64) * K + kk + c4];
            As[c4 + 0][row] = a0.x; As[c4 + 1][row] = a0.y;
            As[c4 + 2][row] = a0.z; As[c4 + 3][row] = a0.w;
            As[c4 + 0][row + 64] = a1.x; As[c4 + 1][row + 64] = a1.y;
            As[c4 + 2][row + 64] = a1.z; As[c4 + 3][row + 64] = a1.w;
        }
        // ---- stage B tile (16 rows x 128 cols) ----
        {
            const int kr = tid >> 5;             // 0..7
            const int c4 = (tid & 31) * 4;       // 0..124
            *(float4*)&Bs[kr][c4]     = *(const float4*)&W[(size_t)(kk + kr) * N + n0 + c4];
            *(float4*)&Bs[kr + 8][c4] = *(const float4*)&W[(size_t)(kk + kr + 8) * N + n0 + c4];
        }
        __syncthreads();

        #pragma unroll
        for (int k = 0; k < BK; ++k) {
            float4 A0 = *(const float4*)&As[k][ty * 4];
            float4 A1 = *(const float4*)&As[k][64 + ty * 4];
            float4 B0 = *(const float4*)&Bs[k][tx * 4];
            float4 B1 = *(const float4*)&Bs[k][64 + tx * 4];
            float av[2][4] = {{A0.x, A0.y, A0.z, A0.w}, {A1.x, A1.y, A1.z, A1.w}};
            float bv[2][4] = {{B0.x, B0.y, B0.z, B0.w}, {B1.x, B1.y, B1.z, B1.w}};
            #pragma unroll
            for (int hi = 0; hi < 2; ++hi)
            #pragma unroll
            for (int i = 0; i < 4; ++i)
            #pragma unroll
            for (int hj = 0; hj < 2; ++hj)
            #pragma unroll
            for (int j = 0; j < 4; ++j)
                acc[hi][hj][i][j] += av[hi][i] * bv[hj][j];
        }
        __syncthreads();
    }

    // ---- epilogue: bias + store (float4) ----
    #pragma unroll
    for (int hi = 0; hi < 2; ++hi) {
        #pragma unroll
        for (int i = 0; i < 4; ++i) {
            const int r = m0 + hi * 64 + ty * 4 + i;
            #pragma unroll
            for (int hj = 0; hj < 2; ++hj) {
                const int n = n0 + hj * 64 + tx * 4;
                float4 bvv = *(const float4*)&bias[n];
                float4 val;
                val.x = acc[hi][hj][i][0] + bvv.x;
                val.y = acc[hi][hj][i][1] + bvv.y;
                val.z = acc[hi][hj][i][2] + bvv.z;
                val.w = acc[hi][hj][i][3] + bvv.w;
                if (QKV) {
                    const int b = r / TT, t = r % TT;
                    const int which = n / CC;
                    const int c = n % CC;
                    const int h = c / DD, d = c % DD;
                    float* dst = (which == 0) ? qb : ((which == 1) ? kb : vb);
                    *(float4*)&dst[(((size_t)b * HH + h) * TT + t) * DD + d] = val;
                } else {
                    *(float4*)&out[(size_t)r * N + n] = val;
                }
            }
        }
    }
}

// ---------------------------------------------------------------------------
// Flash-style causal attention, fp32.
// q,k,v: [B*H, T, D].  y: [B, T, C] with head h at column h*D.
// Block = 256 threads, one (b,h) x 64-query-row tile. 64-key tiles via LDS.
// scale = sqrt(D) = 8 (faithful to the reference's inverted scaling).
// ---------------------------------------------------------------------------
__global__ __launch_bounds__(256)
void attn_kernel(const float* __restrict__ q, const float* __restrict__ k,
                 const float* __restrict__ v, float* __restrict__ y)
{
    __shared__ float Qs[64][68];
    __shared__ float KPs[64][68];   // K tile, reused as P tile
    __shared__ float Vs[64][68];

    const int bh = blockIdx.x;      // 0..63
    const int qt = blockIdx.y;      // 0..31
    const int tid = threadIdx.x;
    const int tx = tid & 15;
    const int ty = tid >> 4;
    const int r0 = ty * 4;          // query row in tile
    const int c0 = tx * 4;          // key col in tile / output d col

    const float* qbase = q + (size_t)bh * TT * DD;
    const float* kbase = k + (size_t)bh * TT * DD;
    const float* vbase = v + (size_t)bh * TT * DD;

    // stage Q tile
    {
        const int row = tid >> 4;        // 0..15
        const int c4  = (tid & 15) * 4;
        #pragma unroll
        for (int pp = 0; pp < 4; ++pp)
            *(float4*)&Qs[row + pp * 16][c4] =
                *(const float4*)&qbase[(size_t)(qt * 64 + row + pp * 16) * DD + c4];
    }

    float mi[4], li[4], O[4][4];
    #pragma unroll
    for (int i = 0; i < 4; ++i) {
        mi[i] = -INFINITY; li[i] = 0.f;
        #pragma unroll
        for (int j = 0; j < 4; ++j) O[i][j] = 0.f;
    }

    for (int kt = 0; kt <= qt; ++kt) {
        // stage K,V tiles
        {
            const int row = tid >> 4;
            const int c4  = (tid & 15) * 4;
            #pragma unroll
            for (int pp = 0; pp < 4; ++pp) {
                *(float4*)&KPs[row + pp * 16][c4] =
                    *(const float4*)&kbase[(size_t)(kt * 64 + row + pp * 16) * DD + c4];
                *(float4*)&Vs[row + pp * 16][c4] =
                    *(const float4*)&vbase[(size_t)(kt * 64 + row + pp * 16) * DD + c4];
            }
        }
        __syncthreads();

        // S = Q K^T  (4x4 per thread)
        float S[4][4] = {};
        for (int d4 = 0; d4 < 64; d4 += 4) {
            float qv[4][4], kv[4][4];
            #pragma unroll
            for (int i = 0; i < 4; ++i) {
                float4 t = *(const float4*)&Qs[r0 + i][d4];
                qv[i][0] = t.x; qv[i][1] = t.y; qv[i][2] = t.z; qv[i][3] = t.w;
            }
            #pragma unroll
            for (int j = 0; j < 4; ++j) {
                float4 t = *(const float4*)&KPs[c0 + j][d4];
                kv[j][0] = t.x; kv[j][1] = t.y; kv[j][2] = t.z; kv[j][3] = t.w;
            }
            #pragma unroll
            for (int i = 0; i < 4; ++i)
            #pragma unroll
            for (int j = 0; j < 4; ++j)
            #pragma unroll
            for (int e = 0; e < 4; ++e)
                S[i][j] += qv[i][e] * kv[j][e];
        }
        __syncthreads();   // done with K tile; about to overwrite with P

        // scale (x8), diagonal-tile mask, online softmax
        const bool diag = (kt == qt);
        float pm[4][4];
        #pragma unroll
        for (int i = 0; i < 4; ++i) {
            float rm = -INFINITY;
            #pragma unroll
            for (int j = 0; j < 4; ++j) {
                float s = S[i][j] * 8.0f;
                if (diag && (c0 + j > r0 + i)) s = -INFINITY;
                S[i][j] = s;
                rm = fmaxf(rm, s);
            }
            #pragma unroll
            for (int o = 1; o < 16; o <<= 1) rm = fmaxf(rm, __shfl_xor(rm, o, 64));
            const float mnew = fmaxf(mi[i], rm);
            const float a = __expf(mi[i] - mnew);   // mi=-inf first iter -> 0
            float rs = 0.f;
            #pragma unroll
            for (int j = 0; j < 4; ++j) {
                float pv = __expf(S[i][j] - mnew);
                pm[i][j] = pv; rs += pv;
            }
            #pragma unroll
            for (int o = 1; o < 16; o <<= 1) rs += __shfl_xor(rs, o, 64);
            li[i] = li[i] * a + rs;
            mi[i] = mnew;
            #pragma unroll
            for (int j = 0; j < 4; ++j) O[i][j] *= a;
        }
        // write P into KPs
        #pragma unroll
        for (int i = 0; i < 4; ++i) {
            float4 t; t.x = pm[i][0]; t.y = pm[i][1]; t.z = pm[i][2]; t.w = pm[i][3];
            *(float4*)&KPs[r0 + i][c0] = t;
        }
        __syncthreads();

        // O += P @ V   (O cols = d0 = c0)
        for (int c4 = 0; c4 < 64; c4 += 4) {
            float pv[4][4], vv[4][4];
            #pragma unroll
            for (int i = 0; i < 4; ++i) {
                float4 t = *(const float4*)&KPs[r0 + i][c4];
                pv[i][0] = t.x; pv[i][1] = t.y; pv[i][2] = t.z; pv[i][3] = t.w;
            }
            #pragma unroll
            for (int cc = 0; cc < 4; ++cc) {
                float4 t = *(const float4*)&Vs[c4 + cc][c0];
                vv[cc][0] = t.x; vv[cc][1] = t.y; vv[cc][2] = t.z; vv[cc][3] = t.w;
            }
            #pragma unroll
            for (int i = 0; i < 4; ++i)
            #pragma unroll
            for (int cc = 0; cc < 4; ++cc)
            #pragma unroll
            for (int j = 0; j < 4; ++j)
                O[i][j] += pv[i][cc] * vv[cc][j];
        }
        __syncthreads();
    }

    // normalize + write y[b, t, h*D + d]
    const int b = bh / HH, h = bh % HH;
    #pragma unroll
    for (int i = 0; i < 4; ++i) {
        const float inv = 1.0f / li[i];
        float4 val;
        val.x = O[i][0] * inv; val.y = O[i][1] * inv;
        val.z = O[i][2] * inv; val.w = O[i][3] * inv;
        const int t = qt * 64 + r0 + i;
        *(float4*)&y[((size_t)b * TT + t) * CC + h * DD + c0] = val;
    }
}

// ---------------------------------------------------------------------------
// kernel_launch
// ws layout (fp32): q[B*H*T*D] | k[...] | v[...] | y[B*T*C]  = 128 MB total
// ---------------------------------------------------------------------------
extern "C" void kernel_launch(void* const* d_in, const int* in_sizes, int n_in,
                              void* d_out, int out_size, void* d_ws, size_t ws_size,
                              hipStream_t stream) {
    const float* x      = (const float*)d_in[0];
    const float* w_attn = (const float*)d_in[1];
    const float* b_attn = (const float*)d_in[2];
    const float* w_proj = (const float*)d_in[3];
    const float* b_proj = (const float*)d_in[4];
    float* out = (float*)d_out;

    const size_t per = (size_t)BB * HH * TT * DD;   // 8,388,608 elems
    float* qb = (float*)d_ws;
    float* kb = qb + per;
    float* vb = kb + per;
    float* yb = vb + per;

    // QKV GEMM + bias + scatter to [B,H,T,D]
    dim3 g1(3 * CC / 128, MM / 128);   // (24, 64)
    gemm_kernel<3 * CC, true><<<g1, 256, 0, stream>>>(x, w_attn, b_attn,
                                                      nullptr, qb, kb, vb);

    // causal flash attention
    dim3 g2(BB * HH, TT / 64);         // (64, 32)
    attn_kernel<<<g2, 256, 0, stream>>>(qb, kb, vb, yb);

    // output projection
    dim3 g3(CC / 128, MM / 128);       // (8, 64)
    gemm_kernel<CC, false><<<g3, 256, 0, stream>>>(yb, w_proj, b_proj,
                                                   out, nullptr, nullptr, nullptr);
}

// Round 2
// 866.905 us; speedup vs baseline: 1.7478x; 1.7478x over previous
//
#include <hip/hip_runtime.h>
#include <cmath>

#define BB 4
#define TT 2048
#define CC 1024
#define HH 16
#define DD 64
#define MM (BB*TT)   // 8192

typedef _Float16 f16x8 __attribute__((ext_vector_type(8)));
typedef float f32x4 __attribute__((ext_vector_type(4)));
typedef unsigned short ushort_t;

__device__ __forceinline__ unsigned short f2h(float f) {
    _Float16 h = (_Float16)f;
    return __builtin_bit_cast(unsigned short, h);
}

// async global->LDS, 16 bytes per lane. LDS dest must be wave-uniform base;
// HW scatters lane i to base + i*16.
__device__ __forceinline__ void gld16(const void* gsrc, void* ldst) {
    void* g = const_cast<void*>(gsrc);
    __builtin_amdgcn_global_load_lds(
        (__attribute__((address_space(1))) void*)g,
        (__attribute__((address_space(3))) void*)ldst,
        16, 0, 0);
}

// ---------------------------------------------------------------------------
// prep: fp32 -> f16 (packed x4)
// ---------------------------------------------------------------------------
__global__ __launch_bounds__(256)
void cvt4_kernel(const float* __restrict__ in, ushort_t* __restrict__ out, long n4) {
    long i = (long)blockIdx.x * blockDim.x + threadIdx.x;
    if (i >= n4) return;
    float4 v = ((const float4*)in)[i];
    ushort4 o;
    o.x = f2h(v.x); o.y = f2h(v.y); o.z = f2h(v.z); o.w = f2h(v.w);
    ((ushort4*)out)[i] = o;
}

// ---------------------------------------------------------------------------
// prep: transpose + convert: in[K][N] fp32 -> out[N][K] f16. 32x32 tiles.
// ---------------------------------------------------------------------------
__global__ __launch_bounds__(256)
void trcvt_kernel(const float* __restrict__ in, ushort_t* __restrict__ out,
                  int K, int N) {
    __shared__ float T[32][33];
    const int tx = threadIdx.x & 31;
    const int ty = threadIdx.x >> 5;         // 0..7
    const int n0 = blockIdx.x * 32;
    const int k0 = blockIdx.y * 32;
    #pragma unroll
    for (int i = 0; i < 4; ++i)
        T[ty + i * 8][tx] = in[(size_t)(k0 + ty + i * 8) * N + n0 + tx];
    __syncthreads();
    #pragma unroll
    for (int i = 0; i < 4; ++i)
        out[(size_t)(n0 + ty + i * 8) * K + k0 + tx] = f2h(T[tx][ty + i * 8]);
}

// ---------------------------------------------------------------------------
// f16 MFMA GEMM (m97 structure): C[M,N] = A[M,1024] @ B[1024,N] + bias
// A: f16 [M][K] row-major. Bt: f16 [N][K] (transposed weights).
// 128x128 tile, BK=32, 256 thr = 4 waves, each wave 64x64 via 4x4 of 16x16x32.
// QKV: scatter fp32 into q/k/v [B,H,T,D]; else fp32 out + bias.
// ---------------------------------------------------------------------------
template<int N, bool QKV>
__global__ __launch_bounds__(256)
void hgemm_kernel(const ushort_t* __restrict__ A, const ushort_t* __restrict__ Bt,
                  const float* __restrict__ bias, float* __restrict__ out,
                  float* __restrict__ qb, float* __restrict__ kb,
                  float* __restrict__ vb)
{
    const int K = 1024;
    __shared__ ushort_t As[128 * 32];   // [row][k] contiguous (global_load_lds order)
    __shared__ ushort_t Bs[128 * 32];   // [col][k] contiguous

    const int tid  = threadIdx.x;
    const int lane = tid & 63;
    const int wave = tid >> 6;           // 0..3
    const int wm   = (wave & 1) * 64;
    const int wn   = (wave >> 1) * 64;
    const int m0   = blockIdx.y * 128;
    const int n0   = blockIdx.x * 128;
    const int lrow = lane & 15;
    const int quad = lane >> 4;          // 0..3

    // staging units: 16B each; u = row*4 + chunk; 512 units per tile
    const int u0 = wave * 64 + lane;     // call 0
    const int u1 = u0 + 256;             // call 1
    const size_t gA0 = (size_t)(m0 + (u0 >> 2)) * K + (u0 & 3) * 8;
    const size_t gA1 = (size_t)(m0 + (u1 >> 2)) * K + (u1 & 3) * 8;
    const size_t gB0 = (size_t)(n0 + (u0 >> 2)) * K + (u0 & 3) * 8;
    const size_t gB1 = (size_t)(n0 + (u1 >> 2)) * K + (u1 & 3) * 8;
    ushort_t* ldsA0 = &As[(wave * 64) * 8];
    ushort_t* ldsA1 = &As[(256 + wave * 64) * 8];
    ushort_t* ldsB0 = &Bs[(wave * 64) * 8];
    ushort_t* ldsB1 = &Bs[(256 + wave * 64) * 8];

    f32x4 acc[4][4];
    const f32x4 z = {0.f, 0.f, 0.f, 0.f};
    #pragma unroll
    for (int mt = 0; mt < 4; ++mt)
        #pragma unroll
        for (int nt = 0; nt < 4; ++nt)
            acc[mt][nt] = z;

    for (int kk = 0; kk < K; kk += 32) {
        gld16(&A[gA0 + kk],  ldsA0);
        gld16(&A[gA1 + kk],  ldsA1);
        gld16(&Bt[gB0 + kk], ldsB0);
        gld16(&Bt[gB1 + kk], ldsB1);
        __syncthreads();   // drains vmcnt before reads

        f16x8 af[4], bf[4];
        #pragma unroll
        for (int mt = 0; mt < 4; ++mt)
            af[mt] = *(const f16x8*)&As[(wm + mt * 16 + lrow) * 32 + quad * 8];
        #pragma unroll
        for (int nt = 0; nt < 4; ++nt)
            bf[nt] = *(const f16x8*)&Bs[(wn + nt * 16 + lrow) * 32 + quad * 8];
        #pragma unroll
        for (int mt = 0; mt < 4; ++mt)
            #pragma unroll
            for (int nt = 0; nt < 4; ++nt)
                acc[mt][nt] = __builtin_amdgcn_mfma_f32_16x16x32_f16(
                    af[mt], bf[nt], acc[mt][nt], 0, 0, 0);
        __syncthreads();   // LDS reuse next iter
    }

    // epilogue: C layout col=lane&15, row=quad*4+reg
    #pragma unroll
    for (int mt = 0; mt < 4; ++mt) {
        const int rbase = m0 + wm + mt * 16 + quad * 4;
        #pragma unroll
        for (int nt = 0; nt < 4; ++nt) {
            const int col = n0 + wn + nt * 16 + lrow;
            const float bv = bias[col];
            #pragma unroll
            for (int r = 0; r < 4; ++r) {
                const float val = acc[mt][nt][r] + bv;
                const int row = rbase + r;
                if (QKV) {
                    const int which = col >> 10;
                    const int c = col & 1023;
                    const int h = c >> 6, d = c & 63;
                    const int b = row >> 11, t = row & 2047;
                    float* dst = (which == 0) ? qb : ((which == 1) ? kb : vb);
                    dst[(((size_t)b * HH + h) * TT + t) * DD + d] = val;
                } else {
                    out[(size_t)row * N + col] = val;
                }
            }
        }
    }
}

// ---------------------------------------------------------------------------
// Flash-style causal attention, fp32 (unchanged from R1 except f16 y output).
// q,k,v: [B*H, T, D] fp32.  yh: [B*T, C] f16.
// ---------------------------------------------------------------------------
__global__ __launch_bounds__(256)
void attn_kernel(const float* __restrict__ q, const float* __restrict__ k,
                 const float* __restrict__ v, ushort_t* __restrict__ yh)
{
    __shared__ float Qs[64][68];
    __shared__ float KPs[64][68];
    __shared__ float Vs[64][68];

    const int bh = blockIdx.x;
    const int qt = blockIdx.y;
    const int tid = threadIdx.x;
    const int tx = tid & 15;
    const int ty = tid >> 4;
    const int r0 = ty * 4;
    const int c0 = tx * 4;

    const float* qbase = q + (size_t)bh * TT * DD;
    const float* kbase = k + (size_t)bh * TT * DD;
    const float* vbase = v + (size_t)bh * TT * DD;

    {
        const int row = tid >> 4;
        const int c4  = (tid & 15) * 4;
        #pragma unroll
        for (int pp = 0; pp < 4; ++pp)
            *(float4*)&Qs[row + pp * 16][c4] =
                *(const float4*)&qbase[(size_t)(qt * 64 + row + pp * 16) * DD + c4];
    }

    float mi[4], li[4], O[4][4];
    #pragma unroll
    for (int i = 0; i < 4; ++i) {
        mi[i] = -INFINITY; li[i] = 0.f;
        #pragma unroll
        for (int j = 0; j < 4; ++j) O[i][j] = 0.f;
    }

    for (int kt = 0; kt <= qt; ++kt) {
        {
            const int row = tid >> 4;
            const int c4  = (tid & 15) * 4;
            #pragma unroll
            for (int pp = 0; pp < 4; ++pp) {
                *(float4*)&KPs[row + pp * 16][c4] =
                    *(const float4*)&kbase[(size_t)(kt * 64 + row + pp * 16) * DD + c4];
                *(float4*)&Vs[row + pp * 16][c4] =
                    *(const float4*)&vbase[(size_t)(kt * 64 + row + pp * 16) * DD + c4];
            }
        }
        __syncthreads();

        float S[4][4] = {};
        for (int d4 = 0; d4 < 64; d4 += 4) {
            float qv[4][4], kv[4][4];
            #pragma unroll
            for (int i = 0; i < 4; ++i) {
                float4 t = *(const float4*)&Qs[r0 + i][d4];
                qv[i][0] = t.x; qv[i][1] = t.y; qv[i][2] = t.z; qv[i][3] = t.w;
            }
            #pragma unroll
            for (int j = 0; j < 4; ++j) {
                float4 t = *(const float4*)&KPs[c0 + j][d4];
                kv[j][0] = t.x; kv[j][1] = t.y; kv[j][2] = t.z; kv[j][3] = t.w;
            }
            #pragma unroll
            for (int i = 0; i < 4; ++i)
            #pragma unroll
            for (int j = 0; j < 4; ++j)
            #pragma unroll
            for (int e = 0; e < 4; ++e)
                S[i][j] += qv[i][e] * kv[j][e];
        }
        __syncthreads();

        const bool diag = (kt == qt);
        float pm[4][4];
        #pragma unroll
        for (int i = 0; i < 4; ++i) {
            float rm = -INFINITY;
            #pragma unroll
            for (int j = 0; j < 4; ++j) {
                float s = S[i][j] * 8.0f;
                if (diag && (c0 + j > r0 + i)) s = -INFINITY;
                S[i][j] = s;
                rm = fmaxf(rm, s);
            }
            #pragma unroll
            for (int o = 1; o < 16; o <<= 1) rm = fmaxf(rm, __shfl_xor(rm, o, 64));
            const float mnew = fmaxf(mi[i], rm);
            const float a = __expf(mi[i] - mnew);
            float rs = 0.f;
            #pragma unroll
            for (int j = 0; j < 4; ++j) {
                float pv = __expf(S[i][j] - mnew);
                pm[i][j] = pv; rs += pv;
            }
            #pragma unroll
            for (int o = 1; o < 16; o <<= 1) rs += __shfl_xor(rs, o, 64);
            li[i] = li[i] * a + rs;
            mi[i] = mnew;
            #pragma unroll
            for (int j = 0; j < 4; ++j) O[i][j] *= a;
        }
        #pragma unroll
        for (int i = 0; i < 4; ++i) {
            float4 t; t.x = pm[i][0]; t.y = pm[i][1]; t.z = pm[i][2]; t.w = pm[i][3];
            *(float4*)&KPs[r0 + i][c0] = t;
        }
        __syncthreads();

        for (int c4 = 0; c4 < 64; c4 += 4) {
            float pv[4][4], vv[4][4];
            #pragma unroll
            for (int i = 0; i < 4; ++i) {
                float4 t = *(const float4*)&KPs[r0 + i][c4];
                pv[i][0] = t.x; pv[i][1] = t.y; pv[i][2] = t.z; pv[i][3] = t.w;
            }
            #pragma unroll
            for (int cc = 0; cc < 4; ++cc) {
                float4 t = *(const float4*)&Vs[c4 + cc][c0];
                vv[cc][0] = t.x; vv[cc][1] = t.y; vv[cc][2] = t.z; vv[cc][3] = t.w;
            }
            #pragma unroll
            for (int i = 0; i < 4; ++i)
            #pragma unroll
            for (int cc = 0; cc < 4; ++cc)
            #pragma unroll
            for (int j = 0; j < 4; ++j)
                O[i][j] += pv[i][cc] * vv[cc][j];
        }
        __syncthreads();
    }

    const int b = bh / HH, h = bh % HH;
    #pragma unroll
    for (int i = 0; i < 4; ++i) {
        const float inv = 1.0f / li[i];
        const int t = qt * 64 + r0 + i;
        ushort4 pk;
        pk.x = f2h(O[i][0] * inv); pk.y = f2h(O[i][1] * inv);
        pk.z = f2h(O[i][2] * inv); pk.w = f2h(O[i][3] * inv);
        *(ushort4*)&yh[((size_t)b * TT + t) * CC + h * DD + c0] = pk;
    }
}

// ---------------------------------------------------------------------------
// ws layout:
//   qb fp32 32MB | kb fp32 32MB | vb fp32 32MB | xh f16 16MB (yh aliases xh)
//   | wat f16 6MB | wpt f16 2MB      total 120 MB
// ---------------------------------------------------------------------------
extern "C" void kernel_launch(void* const* d_in, const int* in_sizes, int n_in,
                              void* d_out, int out_size, void* d_ws, size_t ws_size,
                              hipStream_t stream) {
    const float* x      = (const float*)d_in[0];
    const float* w_attn = (const float*)d_in[1];
    const float* b_attn = (const float*)d_in[2];
    const float* w_proj = (const float*)d_in[3];
    const float* b_proj = (const float*)d_in[4];
    float* out = (float*)d_out;

    const size_t per = (size_t)BB * HH * TT * DD;      // 8,388,608
    float* qb = (float*)d_ws;
    float* kb = qb + per;
    float* vb = kb + per;
    ushort_t* xh  = (ushort_t*)(vb + per);             // 8192*1024 f16
    ushort_t* yh  = xh;                                // alias: xh dead after GEMM1
    ushort_t* wat = xh + (size_t)MM * CC;              // 3072*1024 f16
    ushort_t* wpt = wat + (size_t)3 * CC * CC;         // 1024*1024 f16

    // prep
    cvt4_kernel<<<(MM * CC / 4 + 255) / 256, 256, 0, stream>>>(x, xh, MM * CC / 4);
    trcvt_kernel<<<dim3(3 * CC / 32, CC / 32), 256, 0, stream>>>(w_attn, wat, CC, 3 * CC);
    trcvt_kernel<<<dim3(CC / 32, CC / 32), 256, 0, stream>>>(w_proj, wpt, CC, CC);

    // QKV GEMM + bias + scatter
    hgemm_kernel<3 * CC, true><<<dim3(3 * CC / 128, MM / 128), 256, 0, stream>>>(
        xh, wat, b_attn, nullptr, qb, kb, vb);

    // causal attention (fp32), emits f16 y
    attn_kernel<<<dim3(BB * HH, TT / 64), 256, 0, stream>>>(qb, kb, vb, yh);

    // output projection
    hgemm_kernel<CC, false><<<dim3(CC / 128, MM / 128), 256, 0, stream>>>(
        yh, wpt, b_proj, out, nullptr, nullptr, nullptr);
}

// Round 3
// 314.333 us; speedup vs baseline: 4.8203x; 2.7579x over previous
//
#include <hip/hip_runtime.h>
#include <cmath>

#define BB 4
#define TT 2048
#define CC 1024
#define HH 16
#define DD 64
#define MM (BB*TT)   // 8192

typedef _Float16 f16x8 __attribute__((ext_vector_type(8)));
typedef float f32x4 __attribute__((ext_vector_type(4)));
typedef unsigned short ushort_t;

__device__ __forceinline__ unsigned short f2h(float f) {
    _Float16 h = (_Float16)f;
    return __builtin_bit_cast(unsigned short, h);
}

// async global->LDS, 16 bytes per lane (lane i -> base + i*16).
__device__ __forceinline__ void gld16(const void* gsrc, void* ldst) {
    void* g = const_cast<void*>(gsrc);
    __builtin_amdgcn_global_load_lds(
        (__attribute__((address_space(1))) void*)g,
        (__attribute__((address_space(3))) void*)ldst,
        16, 0, 0);
}

// ---------------------------------------------------------------------------
// prep: fp32 -> f16 (packed x4)
// ---------------------------------------------------------------------------
__global__ __launch_bounds__(256)
void cvt4_kernel(const float* __restrict__ in, ushort_t* __restrict__ out, long n4) {
    long i = (long)blockIdx.x * blockDim.x + threadIdx.x;
    if (i >= n4) return;
    float4 v = ((const float4*)in)[i];
    ushort4 o;
    o.x = f2h(v.x); o.y = f2h(v.y); o.z = f2h(v.z); o.w = f2h(v.w);
    ((ushort4*)out)[i] = o;
}

// ---------------------------------------------------------------------------
// prep: transpose + convert: in[K][N] fp32 -> out[N][K] f16. 32x32 tiles.
// ---------------------------------------------------------------------------
__global__ __launch_bounds__(256)
void trcvt_kernel(const float* __restrict__ in, ushort_t* __restrict__ out,
                  int K, int N) {
    __shared__ float T[32][33];
    const int tx = threadIdx.x & 31;
    const int ty = threadIdx.x >> 5;
    const int n0 = blockIdx.x * 32;
    const int k0 = blockIdx.y * 32;
    #pragma unroll
    for (int i = 0; i < 4; ++i)
        T[ty + i * 8][tx] = in[(size_t)(k0 + ty + i * 8) * N + n0 + tx];
    __syncthreads();
    #pragma unroll
    for (int i = 0; i < 4; ++i)
        out[(size_t)(n0 + ty + i * 8) * K + k0 + tx] = f2h(T[tx][ty + i * 8]);
}

// ---------------------------------------------------------------------------
// f16 MFMA GEMM (m97 structure): C[M,N] = A[M,1024] @ B[1024,N] + bias
// QKV epilogue: q,k f16 [B,H,T,D] (q pre-scaled x8); v f16 TRANSPOSED [B,H,D,T].
// ---------------------------------------------------------------------------
template<int N, bool QKV>
__global__ __launch_bounds__(256)
void hgemm_kernel(const ushort_t* __restrict__ A, const ushort_t* __restrict__ Bt,
                  const float* __restrict__ bias, float* __restrict__ out,
                  ushort_t* __restrict__ qh, ushort_t* __restrict__ kh,
                  ushort_t* __restrict__ vh)
{
    const int K = 1024;
    __shared__ ushort_t As[128 * 32];
    __shared__ ushort_t Bs[128 * 32];

    const int tid  = threadIdx.x;
    const int lane = tid & 63;
    const int wave = tid >> 6;
    const int wm   = (wave & 1) * 64;
    const int wn   = (wave >> 1) * 64;
    const int m0   = blockIdx.y * 128;
    const int n0   = blockIdx.x * 128;
    const int lrow = lane & 15;
    const int quad = lane >> 4;

    const int u0 = wave * 64 + lane;
    const int u1 = u0 + 256;
    const size_t gA0 = (size_t)(m0 + (u0 >> 2)) * K + (u0 & 3) * 8;
    const size_t gA1 = (size_t)(m0 + (u1 >> 2)) * K + (u1 & 3) * 8;
    const size_t gB0 = (size_t)(n0 + (u0 >> 2)) * K + (u0 & 3) * 8;
    const size_t gB1 = (size_t)(n0 + (u1 >> 2)) * K + (u1 & 3) * 8;
    ushort_t* ldsA0 = &As[(wave * 64) * 8];
    ushort_t* ldsA1 = &As[(256 + wave * 64) * 8];
    ushort_t* ldsB0 = &Bs[(wave * 64) * 8];
    ushort_t* ldsB1 = &Bs[(256 + wave * 64) * 8];

    f32x4 acc[4][4];
    const f32x4 z = {0.f, 0.f, 0.f, 0.f};
    #pragma unroll
    for (int mt = 0; mt < 4; ++mt)
        #pragma unroll
        for (int nt = 0; nt < 4; ++nt)
            acc[mt][nt] = z;

    for (int kk = 0; kk < K; kk += 32) {
        gld16(&A[gA0 + kk],  ldsA0);
        gld16(&A[gA1 + kk],  ldsA1);
        gld16(&Bt[gB0 + kk], ldsB0);
        gld16(&Bt[gB1 + kk], ldsB1);
        __syncthreads();

        f16x8 af[4], bf[4];
        #pragma unroll
        for (int mt = 0; mt < 4; ++mt)
            af[mt] = *(const f16x8*)&As[(wm + mt * 16 + lrow) * 32 + quad * 8];
        #pragma unroll
        for (int nt = 0; nt < 4; ++nt)
            bf[nt] = *(const f16x8*)&Bs[(wn + nt * 16 + lrow) * 32 + quad * 8];
        #pragma unroll
        for (int mt = 0; mt < 4; ++mt)
            #pragma unroll
            for (int nt = 0; nt < 4; ++nt)
                acc[mt][nt] = __builtin_amdgcn_mfma_f32_16x16x32_f16(
                    af[mt], bf[nt], acc[mt][nt], 0, 0, 0);
        __syncthreads();
    }

    #pragma unroll
    for (int mt = 0; mt < 4; ++mt) {
        const int rbase = m0 + wm + mt * 16 + quad * 4;
        #pragma unroll
        for (int nt = 0; nt < 4; ++nt) {
            const int col = n0 + wn + nt * 16 + lrow;
            const float bv = bias[col];
            if (QKV) {
                const int which = col >> 10;
                const int c = col & 1023;
                const int h = c >> 6, d = c & 63;
                const int b = rbase >> 11, t0 = rbase & 2047;
                if (which == 2) {
                    ushort4 pk;
                    pk.x = f2h(acc[mt][nt][0] + bv);
                    pk.y = f2h(acc[mt][nt][1] + bv);
                    pk.z = f2h(acc[mt][nt][2] + bv);
                    pk.w = f2h(acc[mt][nt][3] + bv);
                    *(ushort4*)&vh[(((size_t)b * HH + h) * DD + d) * TT + t0] = pk;
                } else {
                    ushort_t* dst = which ? kh : qh;
                    const float sc = which ? 1.0f : 8.0f;   // fold score scale into q
                    #pragma unroll
                    for (int r = 0; r < 4; ++r)
                        dst[(((size_t)b * HH + h) * TT + t0 + r) * DD + d] =
                            f2h((acc[mt][nt][r] + bv) * sc);
                }
            } else {
                #pragma unroll
                for (int r = 0; r < 4; ++r)
                    out[(size_t)(rbase + r) * N + col] = acc[mt][nt][r] + bv;
            }
        }
    }
}

// ---------------------------------------------------------------------------
// MFMA flash attention. qh,kh: f16 [B*H][T][D] (q pre-scaled x8).
// vh: f16 [B*H][D][T] (transposed). yh: f16 [B*T][C].
// Block = 4 waves; wave w owns q rows [qt*64+w*16, +16). 64-key tiles in LDS.
// LDS rows padded to 72 halves -> all b128 ops conflict-free per 16-lane phase.
// ---------------------------------------------------------------------------
__global__ __launch_bounds__(256)
void attn_mfma_kernel(const ushort_t* __restrict__ qh, const ushort_t* __restrict__ kh,
                      const ushort_t* __restrict__ vh, ushort_t* __restrict__ yh)
{
    __shared__ ushort_t Ks[64 * 72];      // [key][d]
    __shared__ ushort_t Vs[64 * 72];      // [d][key]  (V transposed)
    __shared__ ushort_t Ps[4][16 * 72];   // per-wave P strip [q][key]

    const int bh   = blockIdx.x;
    const int qt   = (int)gridDim.y - 1 - (int)blockIdx.y;  // big tiles first
    const int tid  = threadIdx.x;
    const int lane = tid & 63;
    const int w    = tid >> 6;
    const int lrow = lane & 15;
    const int quad = lane >> 4;

    const ushort_t* qbase = qh + (size_t)bh * TT * DD;
    const ushort_t* kbase = kh + (size_t)bh * TT * DD;
    const ushort_t* vbase = vh + (size_t)bh * DD * TT;

    const int q0 = qt * 64 + w * 16;
    // Q A-fragments (one-time): A[m=lrow][k=quad*8+j], halves 0..31 and 32..63
    const f16x8 aq0 = *(const f16x8*)&qbase[(size_t)(q0 + lrow) * DD + quad * 8];
    const f16x8 aq1 = *(const f16x8*)&qbase[(size_t)(q0 + lrow) * DD + 32 + quad * 8];

    // staging: 256 lanes x 2 units of 16B per tile; unit -> row tid>>3, chunk tid&7
    const int ur = tid >> 3;            // 0..31
    const int uc = (tid & 7) * 8;       // halves 0..56

    f32x4 o[4];
    float mi[4], li[4];
    const f32x4 z = {0.f, 0.f, 0.f, 0.f};
    #pragma unroll
    for (int i = 0; i < 4; ++i) { o[i] = z; mi[i] = -1e30f; li[i] = 0.f; }

    for (int kt = 0; kt <= qt; ++kt) {
        // global -> reg
        uint4 kr0 = *(const uint4*)&kbase[(size_t)(kt * 64 + ur) * DD + uc];
        uint4 kr1 = *(const uint4*)&kbase[(size_t)(kt * 64 + ur + 32) * DD + uc];
        uint4 vr0 = *(const uint4*)&vbase[(size_t)ur * TT + kt * 64 + uc];
        uint4 vr1 = *(const uint4*)&vbase[(size_t)(ur + 32) * TT + kt * 64 + uc];
        __syncthreads();                 // previous tile's readers done
        *(uint4*)&Ks[(ur)      * 72 + uc] = kr0;
        *(uint4*)&Ks[(ur + 32) * 72 + uc] = kr1;
        *(uint4*)&Vs[(ur)      * 72 + uc] = vr0;
        *(uint4*)&Vs[(ur + 32) * 72 + uc] = vr1;
        __syncthreads();                 // tile visible

        // S = Q K^T : 4 col-tiles of 16 keys
        f32x4 s[4];
        #pragma unroll
        for (int c = 0; c < 4; ++c) {
            f16x8 b0 = *(const f16x8*)&Ks[(c * 16 + lrow) * 72 + quad * 8];
            f16x8 b1 = *(const f16x8*)&Ks[(c * 16 + lrow) * 72 + 32 + quad * 8];
            s[c] = __builtin_amdgcn_mfma_f32_16x16x32_f16(aq0, b0, z, 0, 0, 0);
            s[c] = __builtin_amdgcn_mfma_f32_16x16x32_f16(aq1, b1, s[c], 0, 0, 0);
        }

        // online softmax (C-layout: row q = q0+quad*4+r, col key = kt*64+c*16+lrow)
        const bool diag = (kt == qt);
        #pragma unroll
        for (int r = 0; r < 4; ++r) {
            if (diag) {
                const int qg = q0 + quad * 4 + r;
                #pragma unroll
                for (int c = 0; c < 4; ++c)
                    if (kt * 64 + c * 16 + lrow > qg) s[c][r] = -1e30f;
            }
            float m = fmaxf(fmaxf(s[0][r], s[1][r]), fmaxf(s[2][r], s[3][r]));
            #pragma unroll
            for (int off = 1; off < 16; off <<= 1)
                m = fmaxf(m, __shfl_xor(m, off, 64));
            const float mnew  = fmaxf(mi[r], m);
            const float alpha = __expf(mi[r] - mnew);
            float rs = 0.f;
            #pragma unroll
            for (int c = 0; c < 4; ++c) {
                const float p = __expf(s[c][r] - mnew);
                rs += p;
                Ps[w][(quad * 4 + r) * 72 + c * 16 + lrow] = f2h(p);
            }
            #pragma unroll
            for (int off = 1; off < 16; off <<= 1)
                rs += __shfl_xor(rs, off, 64);
            li[r] = li[r] * alpha + rs;
            mi[r] = mnew;
            #pragma unroll
            for (int dt = 0; dt < 4; ++dt) o[dt][r] *= alpha;
        }

        // P A-frags (per-wave region; same-wave LDS RAW is in-order)
        f16x8 ap0 = *(const f16x8*)&Ps[w][lrow * 72 + quad * 8];
        f16x8 ap1 = *(const f16x8*)&Ps[w][lrow * 72 + 32 + quad * 8];
        // O += P V : B-frag B[k=key][n=d] from Vs rows (d-contig keys)
        #pragma unroll
        for (int dt = 0; dt < 4; ++dt) {
            f16x8 b0 = *(const f16x8*)&Vs[(dt * 16 + lrow) * 72 + quad * 8];
            f16x8 b1 = *(const f16x8*)&Vs[(dt * 16 + lrow) * 72 + 32 + quad * 8];
            o[dt] = __builtin_amdgcn_mfma_f32_16x16x32_f16(ap0, b0, o[dt], 0, 0, 0);
            o[dt] = __builtin_amdgcn_mfma_f32_16x16x32_f16(ap1, b1, o[dt], 0, 0, 0);
        }
    }

    // normalize + write y f16 [B*T][C]
    const int b = bh >> 4, h = bh & 15;
    #pragma unroll
    for (int r = 0; r < 4; ++r) {
        const float inv = 1.0f / li[r];
        const int t = q0 + quad * 4 + r;
        #pragma unroll
        for (int dt = 0; dt < 4; ++dt)
            yh[((size_t)b * TT + t) * CC + h * 64 + dt * 16 + lrow] =
                f2h(o[dt][r] * inv);
    }
}

// ---------------------------------------------------------------------------
// ws layout (halves): qh | kh | vh (8.39M each) | xh 8.39M (yh aliases xh)
//                     | wat 3.15M | wpt 1.05M     ~ 75 MB
// ---------------------------------------------------------------------------
extern "C" void kernel_launch(void* const* d_in, const int* in_sizes, int n_in,
                              void* d_out, int out_size, void* d_ws, size_t ws_size,
                              hipStream_t stream) {
    const float* x      = (const float*)d_in[0];
    const float* w_attn = (const float*)d_in[1];
    const float* b_attn = (const float*)d_in[2];
    const float* w_proj = (const float*)d_in[3];
    const float* b_proj = (const float*)d_in[4];
    float* out = (float*)d_out;

    const size_t per = (size_t)BB * HH * TT * DD;      // 8,388,608
    ushort_t* qh  = (ushort_t*)d_ws;
    ushort_t* kh  = qh + per;
    ushort_t* vh  = kh + per;
    ushort_t* xh  = vh + per;
    ushort_t* yh  = xh;                                 // alias: xh dead after GEMM1
    ushort_t* wat = xh + (size_t)MM * CC;
    ushort_t* wpt = wat + (size_t)3 * CC * CC;

    cvt4_kernel<<<(MM * CC / 4 + 255) / 256, 256, 0, stream>>>(x, xh, MM * CC / 4);
    trcvt_kernel<<<dim3(3 * CC / 32, CC / 32), 256, 0, stream>>>(w_attn, wat, CC, 3 * CC);
    trcvt_kernel<<<dim3(CC / 32, CC / 32), 256, 0, stream>>>(w_proj, wpt, CC, CC);

    hgemm_kernel<3 * CC, true><<<dim3(3 * CC / 128, MM / 128), 256, 0, stream>>>(
        xh, wat, b_attn, nullptr, qh, kh, vh);

    attn_mfma_kernel<<<dim3(BB * HH, TT / 64), 256, 0, stream>>>(qh, kh, vh, yh);

    hgemm_kernel<CC, false><<<dim3(CC / 128, MM / 128), 256, 0, stream>>>(
        yh, wpt, b_proj, out, nullptr, nullptr, nullptr);
}